// Round 26
// baseline (343.273 us; speedup 1.0000x reference)
//
#include <hip/hip_runtime.h>
#include <hip/hip_bf16.h>

#define H 128
#define TDEPTH 10
#define NPT 1023
#define NTREES 512

typedef unsigned short bf16_t;
typedef unsigned int u32;
typedef __attribute__((ext_vector_type(8))) short bf16x8;
typedef __attribute__((ext_vector_type(4))) float f32x4;

__device__ __forceinline__ float rcp_(float x) { return __builtin_amdgcn_rcpf(x); }
__device__ __forceinline__ float sig_(float x) { return rcp_(1.0f + __expf(-x)); }
__device__ __forceinline__ float th_(float x)  { return 1.0f - 2.0f * rcp_(__expf(2.0f * x) + 1.0f); }
__device__ __forceinline__ float b2f(u32 u) {
    union { float f; u32 u; } v; v.u = u << 16; return v.f;
}
__device__ __forceinline__ bf16_t f2b16(float f) {
    __hip_bfloat16 h = __float2bfloat16(f);
    return *reinterpret_cast<bf16_t*>(&h);
}
__device__ __forceinline__ bf16x8 ld8(const bf16_t* p) {
    return *reinterpret_cast<const bf16x8*>(p);
}
__device__ __forceinline__ bf16x8 ld8c(const char* p) {
    return *reinterpret_cast<const bf16x8*>(p);
}
// async HBM->LDS, 16B per lane (dest = lds base + lane*16)
__device__ __forceinline__ void gload16(const void* g, void* l) {
    __builtin_amdgcn_global_load_lds(
        (const __attribute__((address_space(1))) void*)g,
        (__attribute__((address_space(3))) void*)l, 16, 0, 0);
}
#define MFMA(a,b,c) __builtin_amdgcn_mfma_f32_16x16x32_bf16(a,b,c,0,0,0)

// ---- internal (l7..l0) kernel buffers: x 8KB | h 16KB | c 16KB = 40KB x2
#define R_H  8192
#define R_C  24576
#define BUFSZ 40960

// ---- fused leaf+l8 kernel: xleaf 16KB + xpar 8KB (dbuf) | h 16KB | c 16KB
#define FX_SZ   24576
#define F_H     49152
#define F_C     65536
#define F_LDSSZ 81920

// ---------------------------------------------------------------------------
__global__ void pack_weights(const float* __restrict__ W_iou, const float* __restrict__ U_iou,
                             const float* __restrict__ W_f,   const float* __restrict__ U_f,
                             const float* __restrict__ W_out, bf16_t* __restrict__ Wb)
{
    int i = blockIdx.x * 256 + threadIdx.x;
    if (i < 131072) {
        int k    = i & 127;
        int p    = (i >> 7) & 7;
        int feat = i >> 10;
        float v;
        switch (p) {
            case 0: v = W_iou[(      feat) * H + k]; break;
            case 1: v = W_iou[(128 + feat) * H + k]; break;
            case 2: v = W_iou[(256 + feat) * H + k]; break;
            case 3: v = U_iou[(      feat) * H + k]; break;
            case 4: v = U_iou[(128 + feat) * H + k]; break;
            case 5: v = U_iou[(256 + feat) * H + k]; break;
            case 6: v = W_f  [feat * H + k]; break;
            default: v = U_f [feat * H + k]; break;
        }
        Wb[i] = f2b16(v);
    } else {
        int j = i - 131072;
        int cls = j >> 7, k = j & 127;
        Wb[i] = f2b16(cls < 5 ? W_out[cls * H + k] : 0.0f);
    }
}

__global__ void pack_E(const float* __restrict__ E, bf16_t* __restrict__ Eb)
{
    int i = blockIdx.x * 256 + threadIdx.x;
    Eb[i] = f2b16(E[i]);
}

// ---------------------------------------------------------------------------
// FUSED leaf (l=9) + internal l=8 (R24 structure: all-x staged in LDS).
// ---------------------------------------------------------------------------
__global__ __launch_bounds__(512, 2) void leaf8_fused(
    const int* __restrict__ wordid, const bf16_t* __restrict__ Eb,
    const bf16_t* __restrict__ Wb,
    const float* __restrict__ b_iou, const float* __restrict__ b_Uiou,
    const float* __restrict__ b_Wf,  const float* __restrict__ b_Uf,
    bf16_t* __restrict__ h_cur, bf16_t* __restrict__ c_cur,
    const float* __restrict__ b_out, float* __restrict__ out,
    int t0, int nt)
{
    extern __shared__ __align__(16) char lds_raw[];   // F_LDSSZ

    const int tid  = threadIdx.x;
    const int lane = tid & 63;
    const int w    = tid >> 6;
    const int l15  = lane & 15;
    const int kg   = lane >> 4;
    const int feat = w * 16 + l15;
    const int tilebase = blockIdx.x * nt;

    const float bi  = b_iou[      feat] + b_Uiou[      feat];
    const float bo  = b_iou[128 + feat] + b_Uiou[128 + feat];
    const float bu  = b_iou[256 + feat] + b_Uiou[256 + feat];
    const float bfv = b_Wf[feat] + b_Uf[feat];
    const f32x4 z = {0.f, 0.f, 0.f, 0.f};

    const bf16_t* wbase = Wb + (size_t)feat * 1024 + kg * 8;
    const bf16_t* Wob   = Wb + 131072;

    const int lrow = lane >> 4;
    const int colb = (lane & 15) * 16;

    struct Wids { int a, b, c; };
    auto loadwid = [&](int t) -> Wids {
        Wids r;
        int tb64 = (tilebase + t) * 64, tb32 = (tilebase + t) * 32;
        {   int gl = tb64 + w * 4 + lrow;
            int tt = gl >> 9, ii = gl & 511;
            r.a = wordid[(t0 + tt) * NPT + 511 + ii]; }
        {   int gl = tb64 + 32 + w * 4 + lrow;
            int tt = gl >> 9, ii = gl & 511;
            r.b = wordid[(t0 + tt) * NPT + 511 + ii]; }
        {   int gp = tb32 + w * 4 + lrow;
            int tt = gp >> 8, ii = gp & 255;
            r.c = wordid[(t0 + tt) * NPT + 255 + ii]; }
        return r;
    };

    auto issue = [&](const Wids& wd, char* xbuf) {
        {   int row = w * 4 + lrow;
            gload16((const char*)Eb + (size_t)wd.a * 256 + (colb ^ ((row & 7) << 4)),
                    xbuf + w * 1024); }
        {   int row = 32 + w * 4 + lrow;
            gload16((const char*)Eb + (size_t)wd.b * 256 + (colb ^ ((row & 7) << 4)),
                    xbuf + (w + 8) * 1024); }
        {   int row = w * 4 + lrow;
            gload16((const char*)Eb + (size_t)wd.c * 256 + (colb ^ ((row & 7) << 4)),
                    xbuf + (w + 16) * 1024); }
    };

    Wids wcur = loadwid(0);
    issue(wcur, lds_raw);
    if (nt > 1) wcur = loadwid(1);
    __syncthreads();

    char* h_s = lds_raw + F_H;
    char* c_s = lds_raw + F_C;

    for (int t = 0; t < nt; ++t) {
        char* xbuf  = lds_raw + (t & 1) * FX_SZ;
        char* xleaf = xbuf;
        char* xpar  = xbuf + 16384;
        const int n0 = (tilebase + t) * 32;

        // ---------------- phase 1: leaf cell for 64 children -----------------
        f32x4 lac[3][4];
#pragma unroll
        for (int g = 0; g < 3; ++g)
#pragma unroll
            for (int m = 0; m < 4; ++m) lac[g][m] = z;

#pragma unroll
        for (int ks = 0; ks < 4; ++ks) {
            bf16x8 W0 = ld8(wbase + ks * 32 + 0 * 128);
            bf16x8 W1 = ld8(wbase + ks * 32 + 1 * 128);
            bf16x8 W2 = ld8(wbase + ks * 32 + 2 * 128);
            const int cb = (ks * 32 + kg * 8) * 2;
#pragma unroll
            for (int mt = 0; mt < 4; ++mt) {
                int row = mt * 16 + l15;
                bf16x8 xa = ld8c(xleaf + row * 256 + (cb ^ ((row & 7) << 4)));
                lac[0][mt] = MFMA(xa, W0, lac[0][mt]);
                lac[1][mt] = MFMA(xa, W1, lac[1][mt]);
                lac[2][mt] = MFMA(xa, W2, lac[2][mt]);
            }
        }

        if (t + 1 < nt) {
            issue(wcur, lds_raw + ((t + 1) & 1) * FX_SZ);
            if (t + 2 < nt) wcur = loadwid(t + 2);
        }

        // leaf epilogue -> h/c LDS
#pragma unroll
        for (int mt = 0; mt < 4; ++mt) {
#pragma unroll
            for (int r = 0; r < 4; ++r) {
                int j = mt * 16 + kg * 4 + r;
                float iv = sig_(lac[0][mt][r] + bi);
                float ov = sig_(lac[1][mt][r] + bo);
                float uv = th_ (lac[2][mt][r] + bu);
                float cl = iv * uv;
                float hl = ov * th_(cl);
                int off = j * 256 + ((feat * 2) ^ (((j >> 1) & 7) << 4));
                *(bf16_t*)(h_s + off) = f2b16(hl);
                *(bf16_t*)(c_s + off) = f2b16(cl);
            }
        }
        __syncthreads();

        // ---------------- phase 2: parent cell (32 nodes) --------------------
        f32x4 acc[6][2];
#pragma unroll
        for (int g = 0; g < 6; ++g)
#pragma unroll
            for (int m = 0; m < 2; ++m) acc[g][m] = z;

#pragma unroll
        for (int ks = 0; ks < 4; ++ks) {
            bf16x8 W0 = ld8(wbase + ks * 32 + 0 * 128);
            bf16x8 W1 = ld8(wbase + ks * 32 + 1 * 128);
            bf16x8 W2 = ld8(wbase + ks * 32 + 2 * 128);
            bf16x8 W3 = ld8(wbase + ks * 32 + 3 * 128);
            bf16x8 W4 = ld8(wbase + ks * 32 + 4 * 128);
            bf16x8 W5 = ld8(wbase + ks * 32 + 5 * 128);
            bf16x8 W6 = ld8(wbase + ks * 32 + 6 * 128);
            bf16x8 W7 = ld8(wbase + ks * 32 + 7 * 128);
            const int cb = (ks * 32 + kg * 8) * 2;
#pragma unroll
            for (int mt = 0; mt < 2; ++mt) {
                const int row = mt * 16 + l15;
                const int sw  = (row & 7) << 4;
                bf16x8 xa  = ld8c(xpar + row * 256 + (cb ^ sw));
                bf16x8 h0a = ld8c(h_s + (2 * row)     * 256 + (cb ^ sw));
                bf16x8 h1a = ld8c(h_s + (2 * row + 1) * 256 + (cb ^ sw));
                acc[0][mt] = MFMA(h1a, W3, MFMA(h0a, W3, MFMA(xa, W0, acc[0][mt])));
                acc[1][mt] = MFMA(h1a, W4, MFMA(h0a, W4, MFMA(xa, W1, acc[1][mt])));
                acc[2][mt] = MFMA(h1a, W5, MFMA(h0a, W5, MFMA(xa, W2, acc[2][mt])));
                acc[3][mt] = MFMA(xa,  W6, acc[3][mt]);
                acc[4][mt] = MFMA(h0a, W7, acc[4][mt]);
                acc[5][mt] = MFMA(h1a, W7, acc[5][mt]);
            }
        }

        // leaf (level 9) logits via MFMA: waves 0-3, 16 children each
        if (w < 4) {
            const int pr = (w & 2) ? 1 : 0;
            const int mbase = (w & 1) * 16;
            f32x4 lacc = z;
#pragma unroll
            for (int ks = 0; ks < 4; ++ks) {
                const int cb = (ks * 32 + kg * 8) * 2;
                int prow = mbase + l15;
                bf16x8 ha = ld8c(h_s + (size_t)(2 * prow + pr) * 256
                                 + (cb ^ ((prow & 7) << 4)));
                bf16x8 wo = ld8(Wob + (size_t)l15 * 128 + ks * 32 + kg * 8);
                lacc = MFMA(ha, wo, lacc);
            }
            if (l15 < 5) {
                float bo5 = b_out[l15];
#pragma unroll
                for (int r = 0; r < 4; ++r) {
                    int m  = mbase + kg * 4 + r;
                    int gc = 2 * (n0 + m) + pr;
                    int tt = gc >> 9, ii = gc & 511;
                    out[(size_t)((t0 + tt) * NPT + 511 + ii) * 5 + l15] = lacc[r] + bo5;
                }
            }
        }

        // parent epilogue -> h8/c8 HBM
#pragma unroll
        for (int mt = 0; mt < 2; ++mt) {
#pragma unroll
            for (int r = 0; r < 4; ++r) {
                int nb = mt * 16 + kg * 4 + r;
                int g  = n0 + nb;
                float iv = sig_(acc[0][mt][r] + bi);
                float ov = sig_(acc[1][mt][r] + bo);
                float uv = th_ (acc[2][mt][r] + bu);
                float fx = acc[3][mt][r];
                float f0 = sig_(fx + acc[4][mt][r] + bfv);
                float f1 = sig_(fx + acc[5][mt][r] + bfv);
                int co = (feat * 2) ^ ((nb & 7) << 4);
                float c0 = b2f((u32)*(const bf16_t*)(c_s + (2 * nb)     * 256 + co));
                float c1 = b2f((u32)*(const bf16_t*)(c_s + (2 * nb + 1) * 256 + co));
                float cl = iv * uv + f0 * c0 + f1 * c1;
                float hl = ov * th_(cl);
                h_cur[(size_t)g * H + feat] = f2b16(hl);
                c_cur[(size_t)g * H + feat] = f2b16(cl);
            }
        }

        __syncthreads();
    }
}

// ---------------------------------------------------------------------------
// Internal level (l7..l0): R24 structure — 32-node tiles, double-buffered
// gload_lds pipeline, 2x40KB LDS.
// ---------------------------------------------------------------------------
__global__ __launch_bounds__(512, 2) void internal_mfma(
    const int* __restrict__ wordid, const bf16_t* __restrict__ Eb,
    const bf16_t* __restrict__ Wb,
    const float* __restrict__ b_iou, const float* __restrict__ b_Uiou,
    const float* __restrict__ b_Wf,  const float* __restrict__ b_Uf,
    const bf16_t* __restrict__ h_prev, const bf16_t* __restrict__ c_prev,
    bf16_t* __restrict__ h_cur, bf16_t* __restrict__ c_cur,
    const float* __restrict__ b_out, float* __restrict__ out,
    int level, int t0, int nt)
{
    extern __shared__ __align__(16) char lds_raw[];   // 2 * BUFSZ

    const int tid  = threadIdx.x;
    const int lane = tid & 63;
    const int w    = tid >> 6;
    const int l15  = lane & 15;
    const int kg   = lane >> 4;
    const int feat = w * 16 + l15;
    const int tilebase = blockIdx.x * nt;

    const float bi  = b_iou[      feat] + b_Uiou[      feat];
    const float bo  = b_iou[128 + feat] + b_Uiou[128 + feat];
    const float bu  = b_iou[256 + feat] + b_Uiou[256 + feat];
    const float bfv = b_Wf[feat] + b_Uf[feat];
    const f32x4 z = {0.f, 0.f, 0.f, 0.f};

    const bf16_t* wbase = Wb + (size_t)feat * 1024 + kg * 8;
    const bf16_t* Wob   = Wb + 131072;

    const int lrow = lane >> 4;
    const int colb = (lane & 15) * 16;

    auto issue = [&](int t, char* buf) {
        int n0 = (tilebase + t) * 32;
#pragma unroll
        for (int cc = 0; cc < 5; ++cc) {
            int ch = w + cc * 8;
            const char* src;
            if (ch < 8) {                       // x plane, rows 0..31
                int row = ch * 4 + lrow;
                int g = n0 + row;
                int tt = g >> level, ii = g & ((1 << level) - 1);
                int wid = wordid[(t0 + tt) * NPT + (1 << level) - 1 + ii];
                src = (const char*)Eb + (size_t)wid * 256 + (colb ^ ((row & 7) << 4));
            } else if (ch < 24) {               // h plane, child rows 0..63
                int row = (ch - 8) * 4 + lrow;
                src = (const char*)h_prev + ((size_t)(2 * n0) + row) * 256
                    + (colb ^ (((row >> 1) & 7) << 4));
            } else {                            // c plane, child rows 0..63
                int row = (ch - 24) * 4 + lrow;
                src = (const char*)c_prev + ((size_t)(2 * n0) + row) * 256
                    + (colb ^ (((row >> 1) & 7) << 4));
            }
            gload16(src, buf + ch * 1024);
        }
    };

    issue(0, lds_raw);
    __syncthreads();

    for (int t = 0; t < nt; ++t) {
        char* buf = lds_raw + (t & 1) * BUFSZ;
        char* x_s = buf;
        char* h_s = buf + R_H;
        char* c_s = buf + R_C;
        const int n0 = (tilebase + t) * 32;

        f32x4 acc[6][2];
#pragma unroll
        for (int g = 0; g < 6; ++g)
#pragma unroll
            for (int m = 0; m < 2; ++m) acc[g][m] = z;

#pragma unroll
        for (int ks = 0; ks < 4; ++ks) {
            const int cb = (ks * 32 + kg * 8) * 2;
            bf16x8 W0 = ld8(wbase + ks * 32 + 0 * 128);
            bf16x8 W1 = ld8(wbase + ks * 32 + 1 * 128);
            bf16x8 W2 = ld8(wbase + ks * 32 + 2 * 128);
            bf16x8 W3 = ld8(wbase + ks * 32 + 3 * 128);
            bf16x8 W4 = ld8(wbase + ks * 32 + 4 * 128);
            bf16x8 W5 = ld8(wbase + ks * 32 + 5 * 128);
            bf16x8 W6 = ld8(wbase + ks * 32 + 6 * 128);
            bf16x8 W7 = ld8(wbase + ks * 32 + 7 * 128);
#pragma unroll
            for (int mt = 0; mt < 2; ++mt) {
                const int row = mt * 16 + l15;
                const int sw  = (row & 7) << 4;
                bf16x8 xa  = ld8c(x_s + row * 256 + (cb ^ sw));
                bf16x8 h0a = ld8c(h_s + (2 * row)     * 256 + (cb ^ sw));
                bf16x8 h1a = ld8c(h_s + (2 * row + 1) * 256 + (cb ^ sw));
                acc[0][mt] = MFMA(h1a, W3, MFMA(h0a, W3, MFMA(xa, W0, acc[0][mt])));
                acc[1][mt] = MFMA(h1a, W4, MFMA(h0a, W4, MFMA(xa, W1, acc[1][mt])));
                acc[2][mt] = MFMA(h1a, W5, MFMA(h0a, W5, MFMA(xa, W2, acc[2][mt])));
                acc[3][mt] = MFMA(xa,  W6, acc[3][mt]);
                acc[4][mt] = MFMA(h0a, W7, acc[4][mt]);
                acc[5][mt] = MFMA(h1a, W7, acc[5][mt]);
            }
        }

        // prefetch next tile early
        if (t + 1 < nt) issue(t + 1, lds_raw + ((t + 1) & 1) * BUFSZ);

        // child (level+1) logits via MFMA: waves 0-3, 16 children each
        if (w < 4) {
            const int pr = (w & 2) ? 1 : 0;
            const int mbase = (w & 1) * 16;
            f32x4 lacc = z;
#pragma unroll
            for (int ks = 0; ks < 4; ++ks) {
                const int cb = (ks * 32 + kg * 8) * 2;
                int prow = mbase + l15;
                bf16x8 ha = ld8c(h_s + (size_t)(2 * prow + pr) * 256
                                 + (cb ^ ((prow & 7) << 4)));
                bf16x8 wo = ld8(Wob + (size_t)l15 * 128 + ks * 32 + kg * 8);
                lacc = MFMA(ha, wo, lacc);
            }
            if (l15 < 5) {
                float bo5 = b_out[l15];
                int lc = level + 1;
#pragma unroll
                for (int r = 0; r < 4; ++r) {
                    int m  = mbase + kg * 4 + r;
                    int gc = 2 * (n0 + m) + pr;
                    int tt = gc >> lc, ii = gc & ((1 << lc) - 1);
                    out[(size_t)((t0 + tt) * NPT + (1 << lc) - 1 + ii) * 5 + l15] = lacc[r] + bo5;
                }
            }
        }

        // epilogue
#pragma unroll
        for (int mt = 0; mt < 2; ++mt) {
#pragma unroll
            for (int r = 0; r < 4; ++r) {
                int nb = mt * 16 + kg * 4 + r;
                int g  = n0 + nb;
                float iv = sig_(acc[0][mt][r] + bi);
                float ov = sig_(acc[1][mt][r] + bo);
                float uv = th_ (acc[2][mt][r] + bu);
                float fx = acc[3][mt][r];
                float f0 = sig_(fx + acc[4][mt][r] + bfv);
                float f1 = sig_(fx + acc[5][mt][r] + bfv);
                int co = (feat * 2) ^ ((nb & 7) << 4);
                float c0 = b2f((u32)*(const bf16_t*)(c_s + (2 * nb)     * 256 + co));
                float c1 = b2f((u32)*(const bf16_t*)(c_s + (2 * nb + 1) * 256 + co));
                float cl = iv * uv + f0 * c0 + f1 * c1;
                float hl = ov * th_(cl);
                h_cur[(size_t)g * H + feat] = f2b16(hl);
                c_cur[(size_t)g * H + feat] = f2b16(cl);
            }
        }

        __syncthreads();
    }
}

// ---------------------------------------------------------------------------
__global__ void logits_root(
    const bf16_t* __restrict__ h0buf, const float* __restrict__ W_out,
    const float* __restrict__ b_out, float* __restrict__ out,
    int M, int t0)
{
    int wv     = (blockIdx.x * blockDim.x + threadIdx.x) >> 6;
    int lane   = threadIdx.x & 63;
    int nwaves = (gridDim.x * blockDim.x) >> 6;
    for (int g = wv; g < M; g += nwaves) {
        float h0 = b2f((u32)h0buf[(size_t)g * H + lane]);
        float h1 = b2f((u32)h0buf[(size_t)g * H + 64 + lane]);
#pragma unroll
        for (int c = 0; c < 5; ++c) {
            float p = h0 * W_out[c * H + lane] + h1 * W_out[c * H + 64 + lane];
#pragma unroll
            for (int off = 32; off >= 1; off >>= 1) p += __shfl_xor(p, off, 64);
            if (lane == 0) out[(size_t)(t0 + g) * NPT * 5 + c] = p + b_out[c];
        }
    }
}

// ---------------------------------------------------------------------------
extern "C" void kernel_launch(void* const* d_in, const int* in_sizes, int n_in,
                              void* d_out, int out_size, void* d_ws, size_t ws_size,
                              hipStream_t stream)
{
    (void)in_sizes; (void)n_in; (void)out_size;
    const int*   wordid = (const int*)  d_in[0];
    const float* E      = (const float*)d_in[1];
    const float* W_iou  = (const float*)d_in[2];
    const float* b_iou  = (const float*)d_in[3];
    const float* U_iou  = (const float*)d_in[4];
    const float* b_Uiou = (const float*)d_in[5];
    const float* W_f    = (const float*)d_in[6];
    const float* b_Wf   = (const float*)d_in[7];
    const float* U_f    = (const float*)d_in[8];
    const float* b_Uf   = (const float*)d_in[9];
    const float* W_out  = (const float*)d_in[10];
    const float* b_out  = (const float*)d_in[11];
    float* out = (float*)d_out;

    bf16_t* Wb = (bf16_t*)d_ws;
    bf16_t* Eb = Wb + 133120;
    bf16_t* dyn = Eb + (size_t)32000 * H;
    const size_t fixed_bytes = (133120 + (size_t)32000 * H) * 2;

    // per-tree bytes: (256+256+256+256) rows * 256 B = 262144
    int C = 1;
    while (C < 16 && fixed_bytes + (size_t)(NTREES / C) * 262144u > ws_size) C <<= 1;
    const int T = NTREES / C;

    bf16_t* hA = dyn;
    bf16_t* cA = hA + (size_t)T * 256 * H;
    bf16_t* hB = cA + (size_t)T * 256 * H;
    bf16_t* cB = hB + (size_t)T * 256 * H;

    pack_weights<<<520, 256, 0, stream>>>(W_iou, U_iou, W_f, U_f, W_out, Wb);
    pack_E<<<16000, 256, 0, stream>>>(E, Eb);

    for (int chunk = 0; chunk < C; ++chunk) {
        int t0 = chunk * T;

        // fused l9+l8: 512 blocks -> 2 blocks/CU (grid was the occupancy cap)
        {
            int tiles  = (T << 8) / 32;
            int blocks = tiles < 512 ? tiles : 512;
            int nt     = tiles / blocks;
            leaf8_fused<<<blocks, 512, F_LDSSZ, stream>>>(
                wordid, Eb, Wb, b_iou, b_Uiou, b_Wf, b_Uf,
                hB, cB, b_out, out, t0, nt);
        }

        for (int l = TDEPTH - 3; l >= 0; --l) {   // l = 7..0
            int M = T << l;
            bf16_t* h_cur  = (l & 1) ? hA : hB;
            bf16_t* c_cur  = (l & 1) ? cA : cB;
            bf16_t* h_prev = (l & 1) ? hB : hA;
            bf16_t* c_prev = (l & 1) ? cB : cA;

            int tiles  = M / 32;
            int blocks = tiles < 512 ? tiles : 512;
            if (blocks < 1) blocks = 1;
            int nt     = tiles / blocks;
            internal_mfma<<<blocks, 512, 2 * BUFSZ, stream>>>(
                wordid, Eb, Wb, b_iou, b_Uiou, b_Wf, b_Uf,
                h_prev, c_prev, h_cur, c_cur, b_out, out, l, t0, nt);
        }
        int blocksR = (T / 4 < 4096) ? ((T + 3) / 4) : 4096;
        if (blocksR < 1) blocksR = 1;
        logits_root<<<blocksR, 256, 0, stream>>>(hB, W_out, b_out, out, T, t0);
    }
}

// Round 27
// 321.424 us; speedup vs baseline: 1.0680x; 1.0680x over previous
//
#include <hip/hip_runtime.h>
#include <hip/hip_bf16.h>

#define H 128
#define TDEPTH 10
#define NPT 1023
#define NTREES 512

typedef unsigned short bf16_t;
typedef unsigned int u32;
typedef __attribute__((ext_vector_type(8))) short bf16x8;
typedef __attribute__((ext_vector_type(4))) float f32x4;

__device__ __forceinline__ float rcp_(float x) { return __builtin_amdgcn_rcpf(x); }
__device__ __forceinline__ float sig_(float x) { return rcp_(1.0f + __expf(-x)); }
__device__ __forceinline__ float th_(float x)  { return 1.0f - 2.0f * rcp_(__expf(2.0f * x) + 1.0f); }
__device__ __forceinline__ float b2f(u32 u) {
    union { float f; u32 u; } v; v.u = u << 16; return v.f;
}
__device__ __forceinline__ bf16_t f2b16(float f) {
    __hip_bfloat16 h = __float2bfloat16(f);
    return *reinterpret_cast<bf16_t*>(&h);
}
__device__ __forceinline__ bf16x8 ld8(const bf16_t* p) {
    return *reinterpret_cast<const bf16x8*>(p);
}
__device__ __forceinline__ bf16x8 ld8c(const char* p) {
    return *reinterpret_cast<const bf16x8*>(p);
}
// async HBM->LDS, 16B per lane (dest = lds base + lane*16)
__device__ __forceinline__ void gload16(const void* g, void* l) {
    __builtin_amdgcn_global_load_lds(
        (const __attribute__((address_space(1))) void*)g,
        (__attribute__((address_space(3))) void*)l, 16, 0, 0);
}
#define MFMA(a,b,c) __builtin_amdgcn_mfma_f32_16x16x32_bf16(a,b,c,0,0,0)

// ---- internal (l7..l0) kernel buffers: x 8KB | h 16KB | c 16KB = 40KB x2
#define R_H  8192
#define R_C  24576
#define BUFSZ 40960

// ---- fused leaf+l8: xleaf dbuf 2x16KB | xpar 8KB | h 16KB | c 16KB = 72KB
#define F_XP    32768
#define F_H     40960
#define F_C     57344
#define F_LDSSZ 73728

// ---------------------------------------------------------------------------
__global__ void pack_weights(const float* __restrict__ W_iou, const float* __restrict__ U_iou,
                             const float* __restrict__ W_f,   const float* __restrict__ U_f,
                             const float* __restrict__ W_out, bf16_t* __restrict__ Wb)
{
    int i = blockIdx.x * 256 + threadIdx.x;
    if (i < 131072) {
        int k    = i & 127;
        int p    = (i >> 7) & 7;
        int feat = i >> 10;
        float v;
        switch (p) {
            case 0: v = W_iou[(      feat) * H + k]; break;
            case 1: v = W_iou[(128 + feat) * H + k]; break;
            case 2: v = W_iou[(256 + feat) * H + k]; break;
            case 3: v = U_iou[(      feat) * H + k]; break;
            case 4: v = U_iou[(128 + feat) * H + k]; break;
            case 5: v = U_iou[(256 + feat) * H + k]; break;
            case 6: v = W_f  [feat * H + k]; break;
            default: v = U_f [feat * H + k]; break;
        }
        Wb[i] = f2b16(v);
    } else {
        int j = i - 131072;
        int cls = j >> 7, k = j & 127;
        Wb[i] = f2b16(cls < 5 ? W_out[cls * H + k] : 0.0f);
    }
}

__global__ void pack_E(const float* __restrict__ E, bf16_t* __restrict__ Eb)
{
    int i = blockIdx.x * 256 + threadIdx.x;
    Eb[i] = f2b16(E[i]);
}

// ---------------------------------------------------------------------------
// FUSED leaf (l=9) + internal l=8. xpar single-buffered (issued at tile top,
// lands at mid barrier); xleaf double-buffered. 72KB LDS -> 2 blocks/CU.
// ---------------------------------------------------------------------------
__global__ __launch_bounds__(512, 2) void leaf8_fused(
    const int* __restrict__ wordid, const bf16_t* __restrict__ Eb,
    const bf16_t* __restrict__ Wb,
    const float* __restrict__ b_iou, const float* __restrict__ b_Uiou,
    const float* __restrict__ b_Wf,  const float* __restrict__ b_Uf,
    bf16_t* __restrict__ h_cur, bf16_t* __restrict__ c_cur,
    const float* __restrict__ b_out, float* __restrict__ out,
    int t0, int nt)
{
    extern __shared__ __align__(16) char lds_raw[];   // F_LDSSZ

    const int tid  = threadIdx.x;
    const int lane = tid & 63;
    const int w    = tid >> 6;
    const int l15  = lane & 15;
    const int kg   = lane >> 4;
    const int feat = w * 16 + l15;
    const int tilebase = blockIdx.x * nt;

    const float bi  = b_iou[      feat] + b_Uiou[      feat];
    const float bo  = b_iou[128 + feat] + b_Uiou[128 + feat];
    const float bu  = b_iou[256 + feat] + b_Uiou[256 + feat];
    const float bfv = b_Wf[feat] + b_Uf[feat];
    const f32x4 z = {0.f, 0.f, 0.f, 0.f};

    const bf16_t* wbase = Wb + (size_t)feat * 1024 + kg * 8;
    const bf16_t* Wob   = Wb + 131072;

    const int lrow = lane >> 4;
    const int colb = (lane & 15) * 16;

    struct Wids { int a, b, c; };
    auto loadwid = [&](int t) -> Wids {
        Wids r;
        int tb64 = (tilebase + t) * 64, tb32 = (tilebase + t) * 32;
        {   int gl = tb64 + w * 4 + lrow;
            int tt = gl >> 9, ii = gl & 511;
            r.a = wordid[(t0 + tt) * NPT + 511 + ii]; }
        {   int gl = tb64 + 32 + w * 4 + lrow;
            int tt = gl >> 9, ii = gl & 511;
            r.b = wordid[(t0 + tt) * NPT + 511 + ii]; }
        {   int gp = tb32 + w * 4 + lrow;
            int tt = gp >> 8, ii = gp & 255;
            r.c = wordid[(t0 + tt) * NPT + 255 + ii]; }
        return r;
    };

    auto issue_leaf = [&](const Wids& wd, char* xbuf) {
        {   int row = w * 4 + lrow;
            gload16((const char*)Eb + (size_t)wd.a * 256 + (colb ^ ((row & 7) << 4)),
                    xbuf + w * 1024); }
        {   int row = 32 + w * 4 + lrow;
            gload16((const char*)Eb + (size_t)wd.b * 256 + (colb ^ ((row & 7) << 4)),
                    xbuf + (w + 8) * 1024); }
    };
    auto issue_xpar = [&](int widc) {
        int row = w * 4 + lrow;
        gload16((const char*)Eb + (size_t)widc * 256 + (colb ^ ((row & 7) << 4)),
                lds_raw + F_XP + w * 1024);
    };

    Wids w0 = loadwid(0);
    issue_leaf(w0, lds_raw);
    int pwc = w0.c;                       // xpar wid for current tile
    Wids wcur = (nt > 1) ? loadwid(1) : w0;
    __syncthreads();

    char* h_s = lds_raw + F_H;
    char* c_s = lds_raw + F_C;

    for (int t = 0; t < nt; ++t) {
        char* xleaf = lds_raw + (t & 1) * 16384;
        const int n0 = (tilebase + t) * 32;

        // xpar for THIS tile: previous readers are behind the end barrier;
        // lands at the mid barrier (covered by phase 1)
        issue_xpar(pwc);

        // ---------------- phase 1: leaf cell for 64 children -----------------
        f32x4 lac[3][4];
#pragma unroll
        for (int g = 0; g < 3; ++g)
#pragma unroll
            for (int m = 0; m < 4; ++m) lac[g][m] = z;

#pragma unroll
        for (int ks = 0; ks < 4; ++ks) {
            bf16x8 W0 = ld8(wbase + ks * 32 + 0 * 128);
            bf16x8 W1 = ld8(wbase + ks * 32 + 1 * 128);
            bf16x8 W2 = ld8(wbase + ks * 32 + 2 * 128);
            const int cb = (ks * 32 + kg * 8) * 2;
#pragma unroll
            for (int mt = 0; mt < 4; ++mt) {
                int row = mt * 16 + l15;
                bf16x8 xa = ld8c(xleaf + row * 256 + (cb ^ ((row & 7) << 4)));
                lac[0][mt] = MFMA(xa, W0, lac[0][mt]);
                lac[1][mt] = MFMA(xa, W1, lac[1][mt]);
                lac[2][mt] = MFMA(xa, W2, lac[2][mt]);
            }
        }

        int pwc_next = pwc;
        if (t + 1 < nt) {
            issue_leaf(wcur, lds_raw + ((t + 1) & 1) * 16384);
            pwc_next = wcur.c;
            if (t + 2 < nt) wcur = loadwid(t + 2);
        }

        // leaf epilogue -> h/c LDS
#pragma unroll
        for (int mt = 0; mt < 4; ++mt) {
#pragma unroll
            for (int r = 0; r < 4; ++r) {
                int j = mt * 16 + kg * 4 + r;
                float iv = sig_(lac[0][mt][r] + bi);
                float ov = sig_(lac[1][mt][r] + bo);
                float uv = th_ (lac[2][mt][r] + bu);
                float cl = iv * uv;
                float hl = ov * th_(cl);
                int off = j * 256 + ((feat * 2) ^ (((j >> 1) & 7) << 4));
                *(bf16_t*)(h_s + off) = f2b16(hl);
                *(bf16_t*)(c_s + off) = f2b16(cl);
            }
        }
        __syncthreads();   // h/c visible; drains xpar + leaf prefetch

        // ---------------- phase 2: parent cell (32 nodes) --------------------
        char* xpar = lds_raw + F_XP;
        f32x4 acc[6][2];
#pragma unroll
        for (int g = 0; g < 6; ++g)
#pragma unroll
            for (int m = 0; m < 2; ++m) acc[g][m] = z;

#pragma unroll
        for (int ks = 0; ks < 4; ++ks) {
            bf16x8 W0 = ld8(wbase + ks * 32 + 0 * 128);
            bf16x8 W1 = ld8(wbase + ks * 32 + 1 * 128);
            bf16x8 W2 = ld8(wbase + ks * 32 + 2 * 128);
            bf16x8 W3 = ld8(wbase + ks * 32 + 3 * 128);
            bf16x8 W4 = ld8(wbase + ks * 32 + 4 * 128);
            bf16x8 W5 = ld8(wbase + ks * 32 + 5 * 128);
            bf16x8 W6 = ld8(wbase + ks * 32 + 6 * 128);
            bf16x8 W7 = ld8(wbase + ks * 32 + 7 * 128);
            const int cb = (ks * 32 + kg * 8) * 2;
#pragma unroll
            for (int mt = 0; mt < 2; ++mt) {
                const int row = mt * 16 + l15;
                const int sw  = (row & 7) << 4;
                bf16x8 xa  = ld8c(xpar + row * 256 + (cb ^ sw));
                bf16x8 h0a = ld8c(h_s + (2 * row)     * 256 + (cb ^ sw));
                bf16x8 h1a = ld8c(h_s + (2 * row + 1) * 256 + (cb ^ sw));
                acc[0][mt] = MFMA(h1a, W3, MFMA(h0a, W3, MFMA(xa, W0, acc[0][mt])));
                acc[1][mt] = MFMA(h1a, W4, MFMA(h0a, W4, MFMA(xa, W1, acc[1][mt])));
                acc[2][mt] = MFMA(h1a, W5, MFMA(h0a, W5, MFMA(xa, W2, acc[2][mt])));
                acc[3][mt] = MFMA(xa,  W6, acc[3][mt]);
                acc[4][mt] = MFMA(h0a, W7, acc[4][mt]);
                acc[5][mt] = MFMA(h1a, W7, acc[5][mt]);
            }
        }

        // leaf (level 9) logits via MFMA: waves 0-3, 16 children each
        if (w < 4) {
            const int pr = (w & 2) ? 1 : 0;
            const int mbase = (w & 1) * 16;
            f32x4 lacc = z;
#pragma unroll
            for (int ks = 0; ks < 4; ++ks) {
                const int cb = (ks * 32 + kg * 8) * 2;
                int prow = mbase + l15;
                bf16x8 ha = ld8c(h_s + (size_t)(2 * prow + pr) * 256
                                 + (cb ^ ((prow & 7) << 4)));
                bf16x8 wo = ld8(Wob + (size_t)l15 * 128 + ks * 32 + kg * 8);
                lacc = MFMA(ha, wo, lacc);
            }
            if (l15 < 5) {
                float bo5 = b_out[l15];
#pragma unroll
                for (int r = 0; r < 4; ++r) {
                    int m  = mbase + kg * 4 + r;
                    int gc = 2 * (n0 + m) + pr;
                    int tt = gc >> 9, ii = gc & 511;
                    out[(size_t)((t0 + tt) * NPT + 511 + ii) * 5 + l15] = lacc[r] + bo5;
                }
            }
        }

        // parent epilogue -> h8/c8 HBM
#pragma unroll
        for (int mt = 0; mt < 2; ++mt) {
#pragma unroll
            for (int r = 0; r < 4; ++r) {
                int nb = mt * 16 + kg * 4 + r;
                int g  = n0 + nb;
                float iv = sig_(acc[0][mt][r] + bi);
                float ov = sig_(acc[1][mt][r] + bo);
                float uv = th_ (acc[2][mt][r] + bu);
                float fx = acc[3][mt][r];
                float f0 = sig_(fx + acc[4][mt][r] + bfv);
                float f1 = sig_(fx + acc[5][mt][r] + bfv);
                int co = (feat * 2) ^ ((nb & 7) << 4);
                float c0 = b2f((u32)*(const bf16_t*)(c_s + (2 * nb)     * 256 + co));
                float c1 = b2f((u32)*(const bf16_t*)(c_s + (2 * nb + 1) * 256 + co));
                float cl = iv * uv + f0 * c0 + f1 * c1;
                float hl = ov * th_(cl);
                h_cur[(size_t)g * H + feat] = f2b16(hl);
                c_cur[(size_t)g * H + feat] = f2b16(cl);
            }
        }

        pwc = pwc_next;
        __syncthreads();   // all xpar/h/c readers done before next tile's writes
    }
}

// ---------------------------------------------------------------------------
// Internal level (l7..l0): R24 structure — 32-node tiles, double-buffered
// gload_lds pipeline, 2x40KB LDS, grid 256.
// ---------------------------------------------------------------------------
__global__ __launch_bounds__(512, 2) void internal_mfma(
    const int* __restrict__ wordid, const bf16_t* __restrict__ Eb,
    const bf16_t* __restrict__ Wb,
    const float* __restrict__ b_iou, const float* __restrict__ b_Uiou,
    const float* __restrict__ b_Wf,  const float* __restrict__ b_Uf,
    const bf16_t* __restrict__ h_prev, const bf16_t* __restrict__ c_prev,
    bf16_t* __restrict__ h_cur, bf16_t* __restrict__ c_cur,
    const float* __restrict__ b_out, float* __restrict__ out,
    int level, int t0, int nt)
{
    extern __shared__ __align__(16) char lds_raw[];   // 2 * BUFSZ

    const int tid  = threadIdx.x;
    const int lane = tid & 63;
    const int w    = tid >> 6;
    const int l15  = lane & 15;
    const int kg   = lane >> 4;
    const int feat = w * 16 + l15;
    const int tilebase = blockIdx.x * nt;

    const float bi  = b_iou[      feat] + b_Uiou[      feat];
    const float bo  = b_iou[128 + feat] + b_Uiou[128 + feat];
    const float bu  = b_iou[256 + feat] + b_Uiou[256 + feat];
    const float bfv = b_Wf[feat] + b_Uf[feat];
    const f32x4 z = {0.f, 0.f, 0.f, 0.f};

    const bf16_t* wbase = Wb + (size_t)feat * 1024 + kg * 8;
    const bf16_t* Wob   = Wb + 131072;

    const int lrow = lane >> 4;
    const int colb = (lane & 15) * 16;

    auto issue = [&](int t, char* buf) {
        int n0 = (tilebase + t) * 32;
#pragma unroll
        for (int cc = 0; cc < 5; ++cc) {
            int ch = w + cc * 8;
            const char* src;
            if (ch < 8) {                       // x plane, rows 0..31
                int row = ch * 4 + lrow;
                int g = n0 + row;
                int tt = g >> level, ii = g & ((1 << level) - 1);
                int wid = wordid[(t0 + tt) * NPT + (1 << level) - 1 + ii];
                src = (const char*)Eb + (size_t)wid * 256 + (colb ^ ((row & 7) << 4));
            } else if (ch < 24) {               // h plane, child rows 0..63
                int row = (ch - 8) * 4 + lrow;
                src = (const char*)h_prev + ((size_t)(2 * n0) + row) * 256
                    + (colb ^ (((row >> 1) & 7) << 4));
            } else {                            // c plane, child rows 0..63
                int row = (ch - 24) * 4 + lrow;
                src = (const char*)c_prev + ((size_t)(2 * n0) + row) * 256
                    + (colb ^ (((row >> 1) & 7) << 4));
            }
            gload16(src, buf + ch * 1024);
        }
    };

    issue(0, lds_raw);
    __syncthreads();

    for (int t = 0; t < nt; ++t) {
        char* buf = lds_raw + (t & 1) * BUFSZ;
        char* x_s = buf;
        char* h_s = buf + R_H;
        char* c_s = buf + R_C;
        const int n0 = (tilebase + t) * 32;

        f32x4 acc[6][2];
#pragma unroll
        for (int g = 0; g < 6; ++g)
#pragma unroll
            for (int m = 0; m < 2; ++m) acc[g][m] = z;

#pragma unroll
        for (int ks = 0; ks < 4; ++ks) {
            const int cb = (ks * 32 + kg * 8) * 2;
            bf16x8 W0 = ld8(wbase + ks * 32 + 0 * 128);
            bf16x8 W1 = ld8(wbase + ks * 32 + 1 * 128);
            bf16x8 W2 = ld8(wbase + ks * 32 + 2 * 128);
            bf16x8 W3 = ld8(wbase + ks * 32 + 3 * 128);
            bf16x8 W4 = ld8(wbase + ks * 32 + 4 * 128);
            bf16x8 W5 = ld8(wbase + ks * 32 + 5 * 128);
            bf16x8 W6 = ld8(wbase + ks * 32 + 6 * 128);
            bf16x8 W7 = ld8(wbase + ks * 32 + 7 * 128);
#pragma unroll
            for (int mt = 0; mt < 2; ++mt) {
                const int row = mt * 16 + l15;
                const int sw  = (row & 7) << 4;
                bf16x8 xa  = ld8c(x_s + row * 256 + (cb ^ sw));
                bf16x8 h0a = ld8c(h_s + (2 * row)     * 256 + (cb ^ sw));
                bf16x8 h1a = ld8c(h_s + (2 * row + 1) * 256 + (cb ^ sw));
                acc[0][mt] = MFMA(h1a, W3, MFMA(h0a, W3, MFMA(xa, W0, acc[0][mt])));
                acc[1][mt] = MFMA(h1a, W4, MFMA(h0a, W4, MFMA(xa, W1, acc[1][mt])));
                acc[2][mt] = MFMA(h1a, W5, MFMA(h0a, W5, MFMA(xa, W2, acc[2][mt])));
                acc[3][mt] = MFMA(xa,  W6, acc[3][mt]);
                acc[4][mt] = MFMA(h0a, W7, acc[4][mt]);
                acc[5][mt] = MFMA(h1a, W7, acc[5][mt]);
            }
        }

        // prefetch next tile early
        if (t + 1 < nt) issue(t + 1, lds_raw + ((t + 1) & 1) * BUFSZ);

        // child (level+1) logits via MFMA: waves 0-3, 16 children each
        if (w < 4) {
            const int pr = (w & 2) ? 1 : 0;
            const int mbase = (w & 1) * 16;
            f32x4 lacc = z;
#pragma unroll
            for (int ks = 0; ks < 4; ++ks) {
                const int cb = (ks * 32 + kg * 8) * 2;
                int prow = mbase + l15;
                bf16x8 ha = ld8c(h_s + (size_t)(2 * prow + pr) * 256
                                 + (cb ^ ((prow & 7) << 4)));
                bf16x8 wo = ld8(Wob + (size_t)l15 * 128 + ks * 32 + kg * 8);
                lacc = MFMA(ha, wo, lacc);
            }
            if (l15 < 5) {
                float bo5 = b_out[l15];
                int lc = level + 1;
#pragma unroll
                for (int r = 0; r < 4; ++r) {
                    int m  = mbase + kg * 4 + r;
                    int gc = 2 * (n0 + m) + pr;
                    int tt = gc >> lc, ii = gc & ((1 << lc) - 1);
                    out[(size_t)((t0 + tt) * NPT + (1 << lc) - 1 + ii) * 5 + l15] = lacc[r] + bo5;
                }
            }
        }

        // epilogue
#pragma unroll
        for (int mt = 0; mt < 2; ++mt) {
#pragma unroll
            for (int r = 0; r < 4; ++r) {
                int nb = mt * 16 + kg * 4 + r;
                int g  = n0 + nb;
                float iv = sig_(acc[0][mt][r] + bi);
                float ov = sig_(acc[1][mt][r] + bo);
                float uv = th_ (acc[2][mt][r] + bu);
                float fx = acc[3][mt][r];
                float f0 = sig_(fx + acc[4][mt][r] + bfv);
                float f1 = sig_(fx + acc[5][mt][r] + bfv);
                int co = (feat * 2) ^ ((nb & 7) << 4);
                float c0 = b2f((u32)*(const bf16_t*)(c_s + (2 * nb)     * 256 + co));
                float c1 = b2f((u32)*(const bf16_t*)(c_s + (2 * nb + 1) * 256 + co));
                float cl = iv * uv + f0 * c0 + f1 * c1;
                float hl = ov * th_(cl);
                h_cur[(size_t)g * H + feat] = f2b16(hl);
                c_cur[(size_t)g * H + feat] = f2b16(cl);
            }
        }

        __syncthreads();
    }
}

// ---------------------------------------------------------------------------
__global__ void logits_root(
    const bf16_t* __restrict__ h0buf, const float* __restrict__ W_out,
    const float* __restrict__ b_out, float* __restrict__ out,
    int M, int t0)
{
    int wv     = (blockIdx.x * blockDim.x + threadIdx.x) >> 6;
    int lane   = threadIdx.x & 63;
    int nwaves = (gridDim.x * blockDim.x) >> 6;
    for (int g = wv; g < M; g += nwaves) {
        float h0 = b2f((u32)h0buf[(size_t)g * H + lane]);
        float h1 = b2f((u32)h0buf[(size_t)g * H + 64 + lane]);
#pragma unroll
        for (int c = 0; c < 5; ++c) {
            float p = h0 * W_out[c * H + lane] + h1 * W_out[c * H + 64 + lane];
#pragma unroll
            for (int off = 32; off >= 1; off >>= 1) p += __shfl_xor(p, off, 64);
            if (lane == 0) out[(size_t)(t0 + g) * NPT * 5 + c] = p + b_out[c];
        }
    }
}

// ---------------------------------------------------------------------------
extern "C" void kernel_launch(void* const* d_in, const int* in_sizes, int n_in,
                              void* d_out, int out_size, void* d_ws, size_t ws_size,
                              hipStream_t stream)
{
    (void)in_sizes; (void)n_in; (void)out_size;
    const int*   wordid = (const int*)  d_in[0];
    const float* E      = (const float*)d_in[1];
    const float* W_iou  = (const float*)d_in[2];
    const float* b_iou  = (const float*)d_in[3];
    const float* U_iou  = (const float*)d_in[4];
    const float* b_Uiou = (const float*)d_in[5];
    const float* W_f    = (const float*)d_in[6];
    const float* b_Wf   = (const float*)d_in[7];
    const float* U_f    = (const float*)d_in[8];
    const float* b_Uf   = (const float*)d_in[9];
    const float* W_out  = (const float*)d_in[10];
    const float* b_out  = (const float*)d_in[11];
    float* out = (float*)d_out;

    bf16_t* Wb = (bf16_t*)d_ws;
    bf16_t* Eb = Wb + 133120;
    bf16_t* dyn = Eb + (size_t)32000 * H;
    const size_t fixed_bytes = (133120 + (size_t)32000 * H) * 2;

    // per-tree bytes: (256+256+256+256) rows * 256 B = 262144
    int C = 1;
    while (C < 16 && fixed_bytes + (size_t)(NTREES / C) * 262144u > ws_size) C <<= 1;
    const int T = NTREES / C;

    bf16_t* hA = dyn;
    bf16_t* cA = hA + (size_t)T * 256 * H;
    bf16_t* hB = cA + (size_t)T * 256 * H;
    bf16_t* cB = hB + (size_t)T * 256 * H;

    pack_weights<<<520, 256, 0, stream>>>(W_iou, U_iou, W_f, U_f, W_out, Wb);
    pack_E<<<16000, 256, 0, stream>>>(E, Eb);

    for (int chunk = 0; chunk < C; ++chunk) {
        int t0 = chunk * T;

        // fused l9+l8: 72KB LDS, 512 blocks -> 2 blocks/CU
        {
            int tiles  = (T << 8) / 32;
            int blocks = tiles < 512 ? tiles : 512;
            int nt     = tiles / blocks;
            leaf8_fused<<<blocks, 512, F_LDSSZ, stream>>>(
                wordid, Eb, Wb, b_iou, b_Uiou, b_Wf, b_Uf,
                hB, cB, b_out, out, t0, nt);
        }

        for (int l = TDEPTH - 3; l >= 0; --l) {   // l = 7..0
            int M = T << l;
            bf16_t* h_cur  = (l & 1) ? hA : hB;
            bf16_t* c_cur  = (l & 1) ? cA : cB;
            bf16_t* h_prev = (l & 1) ? hB : hA;
            bf16_t* c_prev = (l & 1) ? cB : cA;

            int tiles  = M / 32;
            int blocks = tiles < 256 ? tiles : 256;
            if (blocks < 1) blocks = 1;
            int nt     = tiles / blocks;
            internal_mfma<<<blocks, 512, 2 * BUFSZ, stream>>>(
                wordid, Eb, Wb, b_iou, b_Uiou, b_Wf, b_Uf,
                h_prev, c_prev, h_cur, c_cur, b_out, out, l, t0, nt);
        }
        int blocksR = (T / 4 < 4096) ? ((T + 3) / 4) : 4096;
        if (blocksR < 1) blocksR = 1;
        logits_root<<<blocksR, 256, 0, stream>>>(hB, W_out, b_out, out, T, t0);
    }
}

// Round 28
// 317.026 us; speedup vs baseline: 1.0828x; 1.0139x over previous
//
#include <hip/hip_runtime.h>
#include <hip/hip_bf16.h>

#define H 128
#define TDEPTH 10
#define NPT 1023
#define NTREES 512

typedef unsigned short bf16_t;
typedef unsigned int u32;
typedef __attribute__((ext_vector_type(8))) short bf16x8;
typedef __attribute__((ext_vector_type(4))) float f32x4;

__device__ __forceinline__ float rcp_(float x) { return __builtin_amdgcn_rcpf(x); }
__device__ __forceinline__ float sig_(float x) { return rcp_(1.0f + __expf(-x)); }
__device__ __forceinline__ float th_(float x)  { return 1.0f - 2.0f * rcp_(__expf(2.0f * x) + 1.0f); }
__device__ __forceinline__ float b2f(u32 u) {
    union { float f; u32 u; } v; v.u = u << 16; return v.f;
}
__device__ __forceinline__ bf16_t f2b16(float f) {
    __hip_bfloat16 h = __float2bfloat16(f);
    return *reinterpret_cast<bf16_t*>(&h);
}
__device__ __forceinline__ bf16x8 ld8(const bf16_t* p) {
    return *reinterpret_cast<const bf16x8*>(p);
}
__device__ __forceinline__ bf16x8 ld8c(const char* p) {
    return *reinterpret_cast<const bf16x8*>(p);
}
// async HBM->LDS, 16B per lane (dest = lds base + lane*16)
__device__ __forceinline__ void gload16(const void* g, void* l) {
    __builtin_amdgcn_global_load_lds(
        (const __attribute__((address_space(1))) void*)g,
        (__attribute__((address_space(3))) void*)l, 16, 0, 0);
}
#define MFMA(a,b,c) __builtin_amdgcn_mfma_f32_16x16x32_bf16(a,b,c,0,0,0)

// ---- internal (l7..l0) kernel buffers: x 8KB | h 16KB | c 16KB = 40KB x2
#define R_H  8192
#define R_C  24576
#define BUFSZ 40960

// ---- fused leaf+l8 kernel: xleaf 16KB + xpar 8KB (dbuf) | h 16KB | c 16KB
#define FX_SZ   24576
#define F_H     49152
#define F_C     65536
#define F_LDSSZ 81920

// ---------------------------------------------------------------------------
__global__ void pack_weights(const float* __restrict__ W_iou, const float* __restrict__ U_iou,
                             const float* __restrict__ W_f,   const float* __restrict__ U_f,
                             const float* __restrict__ W_out, bf16_t* __restrict__ Wb)
{
    int i = blockIdx.x * 256 + threadIdx.x;
    if (i < 131072) {
        int k    = i & 127;
        int p    = (i >> 7) & 7;
        int feat = i >> 10;
        float v;
        switch (p) {
            case 0: v = W_iou[(      feat) * H + k]; break;
            case 1: v = W_iou[(128 + feat) * H + k]; break;
            case 2: v = W_iou[(256 + feat) * H + k]; break;
            case 3: v = U_iou[(      feat) * H + k]; break;
            case 4: v = U_iou[(128 + feat) * H + k]; break;
            case 5: v = U_iou[(256 + feat) * H + k]; break;
            case 6: v = W_f  [feat * H + k]; break;
            default: v = U_f [feat * H + k]; break;
        }
        Wb[i] = f2b16(v);
    } else {
        int j = i - 131072;
        int cls = j >> 7, k = j & 127;
        Wb[i] = f2b16(cls < 5 ? W_out[cls * H + k] : 0.0f);
    }
}

__global__ void pack_E(const float* __restrict__ E, bf16_t* __restrict__ Eb)
{
    int i = blockIdx.x * 256 + threadIdx.x;
    Eb[i] = f2b16(E[i]);
}

// ---------------------------------------------------------------------------
// FUSED leaf (l=9) + internal l=8 (best-measured configuration, R24).
// ---------------------------------------------------------------------------
__global__ __launch_bounds__(512, 2) void leaf8_fused(
    const int* __restrict__ wordid, const bf16_t* __restrict__ Eb,
    const bf16_t* __restrict__ Wb,
    const float* __restrict__ b_iou, const float* __restrict__ b_Uiou,
    const float* __restrict__ b_Wf,  const float* __restrict__ b_Uf,
    bf16_t* __restrict__ h_cur, bf16_t* __restrict__ c_cur,
    const float* __restrict__ b_out, float* __restrict__ out,
    int t0, int nt)
{
    extern __shared__ __align__(16) char lds_raw[];   // F_LDSSZ

    const int tid  = threadIdx.x;
    const int lane = tid & 63;
    const int w    = tid >> 6;
    const int l15  = lane & 15;
    const int kg   = lane >> 4;
    const int feat = w * 16 + l15;
    const int tilebase = blockIdx.x * nt;

    const float bi  = b_iou[      feat] + b_Uiou[      feat];
    const float bo  = b_iou[128 + feat] + b_Uiou[128 + feat];
    const float bu  = b_iou[256 + feat] + b_Uiou[256 + feat];
    const float bfv = b_Wf[feat] + b_Uf[feat];
    const f32x4 z = {0.f, 0.f, 0.f, 0.f};

    const bf16_t* wbase = Wb + (size_t)feat * 1024 + kg * 8;
    const bf16_t* Wob   = Wb + 131072;

    const int lrow = lane >> 4;
    const int colb = (lane & 15) * 16;

    struct Wids { int a, b, c; };
    auto loadwid = [&](int t) -> Wids {
        Wids r;
        int tb64 = (tilebase + t) * 64, tb32 = (tilebase + t) * 32;
        {   int gl = tb64 + w * 4 + lrow;
            int tt = gl >> 9, ii = gl & 511;
            r.a = wordid[(t0 + tt) * NPT + 511 + ii]; }
        {   int gl = tb64 + 32 + w * 4 + lrow;
            int tt = gl >> 9, ii = gl & 511;
            r.b = wordid[(t0 + tt) * NPT + 511 + ii]; }
        {   int gp = tb32 + w * 4 + lrow;
            int tt = gp >> 8, ii = gp & 255;
            r.c = wordid[(t0 + tt) * NPT + 255 + ii]; }
        return r;
    };

    auto issue = [&](const Wids& wd, char* xbuf) {
        {   int row = w * 4 + lrow;
            gload16((const char*)Eb + (size_t)wd.a * 256 + (colb ^ ((row & 7) << 4)),
                    xbuf + w * 1024); }
        {   int row = 32 + w * 4 + lrow;
            gload16((const char*)Eb + (size_t)wd.b * 256 + (colb ^ ((row & 7) << 4)),
                    xbuf + (w + 8) * 1024); }
        {   int row = w * 4 + lrow;
            gload16((const char*)Eb + (size_t)wd.c * 256 + (colb ^ ((row & 7) << 4)),
                    xbuf + (w + 16) * 1024); }
    };

    Wids wcur = loadwid(0);
    issue(wcur, lds_raw);
    if (nt > 1) wcur = loadwid(1);
    __syncthreads();

    char* h_s = lds_raw + F_H;
    char* c_s = lds_raw + F_C;

    for (int t = 0; t < nt; ++t) {
        char* xbuf  = lds_raw + (t & 1) * FX_SZ;
        char* xleaf = xbuf;
        char* xpar  = xbuf + 16384;
        const int n0 = (tilebase + t) * 32;

        // ---------------- phase 1: leaf cell for 64 children -----------------
        f32x4 lac[3][4];
#pragma unroll
        for (int g = 0; g < 3; ++g)
#pragma unroll
            for (int m = 0; m < 4; ++m) lac[g][m] = z;

#pragma unroll
        for (int ks = 0; ks < 4; ++ks) {
            bf16x8 W0 = ld8(wbase + ks * 32 + 0 * 128);
            bf16x8 W1 = ld8(wbase + ks * 32 + 1 * 128);
            bf16x8 W2 = ld8(wbase + ks * 32 + 2 * 128);
            const int cb = (ks * 32 + kg * 8) * 2;
#pragma unroll
            for (int mt = 0; mt < 4; ++mt) {
                int row = mt * 16 + l15;
                bf16x8 xa = ld8c(xleaf + row * 256 + (cb ^ ((row & 7) << 4)));
                lac[0][mt] = MFMA(xa, W0, lac[0][mt]);
                lac[1][mt] = MFMA(xa, W1, lac[1][mt]);
                lac[2][mt] = MFMA(xa, W2, lac[2][mt]);
            }
        }

        if (t + 1 < nt) {
            issue(wcur, lds_raw + ((t + 1) & 1) * FX_SZ);
            if (t + 2 < nt) wcur = loadwid(t + 2);
        }

        // leaf epilogue -> h/c LDS
#pragma unroll
        for (int mt = 0; mt < 4; ++mt) {
#pragma unroll
            for (int r = 0; r < 4; ++r) {
                int j = mt * 16 + kg * 4 + r;
                float iv = sig_(lac[0][mt][r] + bi);
                float ov = sig_(lac[1][mt][r] + bo);
                float uv = th_ (lac[2][mt][r] + bu);
                float cl = iv * uv;
                float hl = ov * th_(cl);
                int off = j * 256 + ((feat * 2) ^ (((j >> 1) & 7) << 4));
                *(bf16_t*)(h_s + off) = f2b16(hl);
                *(bf16_t*)(c_s + off) = f2b16(cl);
            }
        }
        __syncthreads();

        // ---------------- phase 2: parent cell (32 nodes) --------------------
        f32x4 acc[6][2];
#pragma unroll
        for (int g = 0; g < 6; ++g)
#pragma unroll
            for (int m = 0; m < 2; ++m) acc[g][m] = z;

#pragma unroll
        for (int ks = 0; ks < 4; ++ks) {
            bf16x8 W0 = ld8(wbase + ks * 32 + 0 * 128);
            bf16x8 W1 = ld8(wbase + ks * 32 + 1 * 128);
            bf16x8 W2 = ld8(wbase + ks * 32 + 2 * 128);
            bf16x8 W3 = ld8(wbase + ks * 32 + 3 * 128);
            bf16x8 W4 = ld8(wbase + ks * 32 + 4 * 128);
            bf16x8 W5 = ld8(wbase + ks * 32 + 5 * 128);
            bf16x8 W6 = ld8(wbase + ks * 32 + 6 * 128);
            bf16x8 W7 = ld8(wbase + ks * 32 + 7 * 128);
            const int cb = (ks * 32 + kg * 8) * 2;
#pragma unroll
            for (int mt = 0; mt < 2; ++mt) {
                const int row = mt * 16 + l15;
                const int sw  = (row & 7) << 4;
                bf16x8 xa  = ld8c(xpar + row * 256 + (cb ^ sw));
                bf16x8 h0a = ld8c(h_s + (2 * row)     * 256 + (cb ^ sw));
                bf16x8 h1a = ld8c(h_s + (2 * row + 1) * 256 + (cb ^ sw));
                acc[0][mt] = MFMA(h1a, W3, MFMA(h0a, W3, MFMA(xa, W0, acc[0][mt])));
                acc[1][mt] = MFMA(h1a, W4, MFMA(h0a, W4, MFMA(xa, W1, acc[1][mt])));
                acc[2][mt] = MFMA(h1a, W5, MFMA(h0a, W5, MFMA(xa, W2, acc[2][mt])));
                acc[3][mt] = MFMA(xa,  W6, acc[3][mt]);
                acc[4][mt] = MFMA(h0a, W7, acc[4][mt]);
                acc[5][mt] = MFMA(h1a, W7, acc[5][mt]);
            }
        }

        // leaf (level 9) logits via MFMA: waves 0-3, 16 children each
        if (w < 4) {
            const int pr = (w & 2) ? 1 : 0;
            const int mbase = (w & 1) * 16;
            f32x4 lacc = z;
#pragma unroll
            for (int ks = 0; ks < 4; ++ks) {
                const int cb = (ks * 32 + kg * 8) * 2;
                int prow = mbase + l15;
                bf16x8 ha = ld8c(h_s + (size_t)(2 * prow + pr) * 256
                                 + (cb ^ ((prow & 7) << 4)));
                bf16x8 wo = ld8(Wob + (size_t)l15 * 128 + ks * 32 + kg * 8);
                lacc = MFMA(ha, wo, lacc);
            }
            if (l15 < 5) {
                float bo5 = b_out[l15];
#pragma unroll
                for (int r = 0; r < 4; ++r) {
                    int m  = mbase + kg * 4 + r;
                    int gc = 2 * (n0 + m) + pr;
                    int tt = gc >> 9, ii = gc & 511;
                    out[(size_t)((t0 + tt) * NPT + 511 + ii) * 5 + l15] = lacc[r] + bo5;
                }
            }
        }

        // parent epilogue -> h8/c8 HBM
#pragma unroll
        for (int mt = 0; mt < 2; ++mt) {
#pragma unroll
            for (int r = 0; r < 4; ++r) {
                int nb = mt * 16 + kg * 4 + r;
                int g  = n0 + nb;
                float iv = sig_(acc[0][mt][r] + bi);
                float ov = sig_(acc[1][mt][r] + bo);
                float uv = th_ (acc[2][mt][r] + bu);
                float fx = acc[3][mt][r];
                float f0 = sig_(fx + acc[4][mt][r] + bfv);
                float f1 = sig_(fx + acc[5][mt][r] + bfv);
                int co = (feat * 2) ^ ((nb & 7) << 4);
                float c0 = b2f((u32)*(const bf16_t*)(c_s + (2 * nb)     * 256 + co));
                float c1 = b2f((u32)*(const bf16_t*)(c_s + (2 * nb + 1) * 256 + co));
                float cl = iv * uv + f0 * c0 + f1 * c1;
                float hl = ov * th_(cl);
                h_cur[(size_t)g * H + feat] = f2b16(hl);
                c_cur[(size_t)g * H + feat] = f2b16(cl);
            }
        }

        __syncthreads();
    }
}

// ---------------------------------------------------------------------------
// Internal level (l7..l0): 32-node tiles, nt tiles/block, double-buffered
// gload_lds pipeline, 2x40KB LDS.
// ---------------------------------------------------------------------------
__global__ __launch_bounds__(512, 2) void internal_mfma(
    const int* __restrict__ wordid, const bf16_t* __restrict__ Eb,
    const bf16_t* __restrict__ Wb,
    const float* __restrict__ b_iou, const float* __restrict__ b_Uiou,
    const float* __restrict__ b_Wf,  const float* __restrict__ b_Uf,
    const bf16_t* __restrict__ h_prev, const bf16_t* __restrict__ c_prev,
    bf16_t* __restrict__ h_cur, bf16_t* __restrict__ c_cur,
    const float* __restrict__ b_out, float* __restrict__ out,
    int level, int t0, int nt)
{
    extern __shared__ __align__(16) char lds_raw[];   // 2 * BUFSZ

    const int tid  = threadIdx.x;
    const int lane = tid & 63;
    const int w    = tid >> 6;
    const int l15  = lane & 15;
    const int kg   = lane >> 4;
    const int feat = w * 16 + l15;
    const int tilebase = blockIdx.x * nt;

    const float bi  = b_iou[      feat] + b_Uiou[      feat];
    const float bo  = b_iou[128 + feat] + b_Uiou[128 + feat];
    const float bu  = b_iou[256 + feat] + b_Uiou[256 + feat];
    const float bfv = b_Wf[feat] + b_Uf[feat];
    const f32x4 z = {0.f, 0.f, 0.f, 0.f};

    const bf16_t* wbase = Wb + (size_t)feat * 1024 + kg * 8;
    const bf16_t* Wob   = Wb + 131072;

    const int lrow = lane >> 4;
    const int colb = (lane & 15) * 16;

    auto issue = [&](int t, char* buf) {
        int n0 = (tilebase + t) * 32;
#pragma unroll
        for (int cc = 0; cc < 5; ++cc) {
            int ch = w + cc * 8;
            const char* src;
            if (ch < 8) {                       // x plane, rows 0..31
                int row = ch * 4 + lrow;
                int g = n0 + row;
                int tt = g >> level, ii = g & ((1 << level) - 1);
                int wid = wordid[(t0 + tt) * NPT + (1 << level) - 1 + ii];
                src = (const char*)Eb + (size_t)wid * 256 + (colb ^ ((row & 7) << 4));
            } else if (ch < 24) {               // h plane, child rows 0..63
                int row = (ch - 8) * 4 + lrow;
                src = (const char*)h_prev + ((size_t)(2 * n0) + row) * 256
                    + (colb ^ (((row >> 1) & 7) << 4));
            } else {                            // c plane, child rows 0..63
                int row = (ch - 24) * 4 + lrow;
                src = (const char*)c_prev + ((size_t)(2 * n0) + row) * 256
                    + (colb ^ (((row >> 1) & 7) << 4));
            }
            gload16(src, buf + ch * 1024);
        }
    };

    issue(0, lds_raw);
    __syncthreads();

    for (int t = 0; t < nt; ++t) {
        char* buf = lds_raw + (t & 1) * BUFSZ;
        char* x_s = buf;
        char* h_s = buf + R_H;
        char* c_s = buf + R_C;
        const int n0 = (tilebase + t) * 32;

        f32x4 acc[6][2];
#pragma unroll
        for (int g = 0; g < 6; ++g)
#pragma unroll
            for (int m = 0; m < 2; ++m) acc[g][m] = z;

#pragma unroll
        for (int ks = 0; ks < 4; ++ks) {
            const int cb = (ks * 32 + kg * 8) * 2;
            bf16x8 W0 = ld8(wbase + ks * 32 + 0 * 128);
            bf16x8 W1 = ld8(wbase + ks * 32 + 1 * 128);
            bf16x8 W2 = ld8(wbase + ks * 32 + 2 * 128);
            bf16x8 W3 = ld8(wbase + ks * 32 + 3 * 128);
            bf16x8 W4 = ld8(wbase + ks * 32 + 4 * 128);
            bf16x8 W5 = ld8(wbase + ks * 32 + 5 * 128);
            bf16x8 W6 = ld8(wbase + ks * 32 + 6 * 128);
            bf16x8 W7 = ld8(wbase + ks * 32 + 7 * 128);
#pragma unroll
            for (int mt = 0; mt < 2; ++mt) {
                const int row = mt * 16 + l15;
                const int sw  = (row & 7) << 4;
                bf16x8 xa  = ld8c(x_s + row * 256 + (cb ^ sw));
                bf16x8 h0a = ld8c(h_s + (2 * row)     * 256 + (cb ^ sw));
                bf16x8 h1a = ld8c(h_s + (2 * row + 1) * 256 + (cb ^ sw));
                acc[0][mt] = MFMA(h1a, W3, MFMA(h0a, W3, MFMA(xa, W0, acc[0][mt])));
                acc[1][mt] = MFMA(h1a, W4, MFMA(h0a, W4, MFMA(xa, W1, acc[1][mt])));
                acc[2][mt] = MFMA(h1a, W5, MFMA(h0a, W5, MFMA(xa, W2, acc[2][mt])));
                acc[3][mt] = MFMA(xa,  W6, acc[3][mt]);
                acc[4][mt] = MFMA(h0a, W7, acc[4][mt]);
                acc[5][mt] = MFMA(h1a, W7, acc[5][mt]);
            }
        }

        // prefetch next tile early
        if (t + 1 < nt) issue(t + 1, lds_raw + ((t + 1) & 1) * BUFSZ);

        // child (level+1) logits via MFMA: waves 0-3, 16 children each
        if (w < 4) {
            const int pr = (w & 2) ? 1 : 0;
            const int mbase = (w & 1) * 16;
            f32x4 lacc = z;
#pragma unroll
            for (int ks = 0; ks < 4; ++ks) {
                const int cb = (ks * 32 + kg * 8) * 2;
                int prow = mbase + l15;
                bf16x8 ha = ld8c(h_s + (size_t)(2 * prow + pr) * 256
                                 + (cb ^ ((prow & 7) << 4)));
                bf16x8 wo = ld8(Wob + (size_t)l15 * 128 + ks * 32 + kg * 8);
                lacc = MFMA(ha, wo, lacc);
            }
            if (l15 < 5) {
                float bo5 = b_out[l15];
                int lc = level + 1;
#pragma unroll
                for (int r = 0; r < 4; ++r) {
                    int m  = mbase + kg * 4 + r;
                    int gc = 2 * (n0 + m) + pr;
                    int tt = gc >> lc, ii = gc & ((1 << lc) - 1);
                    out[(size_t)((t0 + tt) * NPT + (1 << lc) - 1 + ii) * 5 + l15] = lacc[r] + bo5;
                }
            }
        }

        // epilogue
#pragma unroll
        for (int mt = 0; mt < 2; ++mt) {
#pragma unroll
            for (int r = 0; r < 4; ++r) {
                int nb = mt * 16 + kg * 4 + r;
                int g  = n0 + nb;
                float iv = sig_(acc[0][mt][r] + bi);
                float ov = sig_(acc[1][mt][r] + bo);
                float uv = th_ (acc[2][mt][r] + bu);
                float fx = acc[3][mt][r];
                float f0 = sig_(fx + acc[4][mt][r] + bfv);
                float f1 = sig_(fx + acc[5][mt][r] + bfv);
                int co = (feat * 2) ^ ((nb & 7) << 4);
                float c0 = b2f((u32)*(const bf16_t*)(c_s + (2 * nb)     * 256 + co));
                float c1 = b2f((u32)*(const bf16_t*)(c_s + (2 * nb + 1) * 256 + co));
                float cl = iv * uv + f0 * c0 + f1 * c1;
                float hl = ov * th_(cl);
                h_cur[(size_t)g * H + feat] = f2b16(hl);
                c_cur[(size_t)g * H + feat] = f2b16(cl);
            }
        }

        __syncthreads();
    }
}

// ---------------------------------------------------------------------------
__global__ void logits_root(
    const bf16_t* __restrict__ h0buf, const float* __restrict__ W_out,
    const float* __restrict__ b_out, float* __restrict__ out,
    int M, int t0)
{
    int wv     = (blockIdx.x * blockDim.x + threadIdx.x) >> 6;
    int lane   = threadIdx.x & 63;
    int nwaves = (gridDim.x * blockDim.x) >> 6;
    for (int g = wv; g < M; g += nwaves) {
        float h0 = b2f((u32)h0buf[(size_t)g * H + lane]);
        float h1 = b2f((u32)h0buf[(size_t)g * H + 64 + lane]);
#pragma unroll
        for (int c = 0; c < 5; ++c) {
            float p = h0 * W_out[c * H + lane] + h1 * W_out[c * H + 64 + lane];
#pragma unroll
            for (int off = 32; off >= 1; off >>= 1) p += __shfl_xor(p, off, 64);
            if (lane == 0) out[(size_t)(t0 + g) * NPT * 5 + c] = p + b_out[c];
        }
    }
}

// ---------------------------------------------------------------------------
extern "C" void kernel_launch(void* const* d_in, const int* in_sizes, int n_in,
                              void* d_out, int out_size, void* d_ws, size_t ws_size,
                              hipStream_t stream)
{
    (void)in_sizes; (void)n_in; (void)out_size;
    const int*   wordid = (const int*)  d_in[0];
    const float* E      = (const float*)d_in[1];
    const float* W_iou  = (const float*)d_in[2];
    const float* b_iou  = (const float*)d_in[3];
    const float* U_iou  = (const float*)d_in[4];
    const float* b_Uiou = (const float*)d_in[5];
    const float* W_f    = (const float*)d_in[6];
    const float* b_Wf   = (const float*)d_in[7];
    const float* U_f    = (const float*)d_in[8];
    const float* b_Uf   = (const float*)d_in[9];
    const float* W_out  = (const float*)d_in[10];
    const float* b_out  = (const float*)d_in[11];
    float* out = (float*)d_out;

    bf16_t* Wb = (bf16_t*)d_ws;
    bf16_t* Eb = Wb + 133120;
    bf16_t* dyn = Eb + (size_t)32000 * H;
    const size_t fixed_bytes = (133120 + (size_t)32000 * H) * 2;

    // per-tree bytes: (256+256+256+256) rows * 256 B = 262144
    int C = 1;
    while (C < 16 && fixed_bytes + (size_t)(NTREES / C) * 262144u > ws_size) C <<= 1;
    const int T = NTREES / C;

    bf16_t* hA = dyn;
    bf16_t* cA = hA + (size_t)T * 256 * H;
    bf16_t* hB = cA + (size_t)T * 256 * H;
    bf16_t* cB = hB + (size_t)T * 256 * H;

    pack_weights<<<520, 256, 0, stream>>>(W_iou, U_iou, W_f, U_f, W_out, Wb);
    pack_E<<<16000, 256, 0, stream>>>(E, Eb);

    for (int chunk = 0; chunk < C; ++chunk) {
        int t0 = chunk * T;

        // fused l9+l8
        {
            int tiles  = (T << 8) / 32;
            int blocks = tiles < 256 ? tiles : 256;
            int nt     = tiles / blocks;
            leaf8_fused<<<blocks, 512, F_LDSSZ, stream>>>(
                wordid, Eb, Wb, b_iou, b_Uiou, b_Wf, b_Uf,
                hB, cB, b_out, out, t0, nt);
        }

        for (int l = TDEPTH - 3; l >= 0; --l) {   // l = 7..0
            int M = T << l;
            bf16_t* h_cur  = (l & 1) ? hA : hB;
            bf16_t* c_cur  = (l & 1) ? cA : cB;
            bf16_t* h_prev = (l & 1) ? hB : hA;
            bf16_t* c_prev = (l & 1) ? cB : cA;

            int tiles  = M / 32;
            int blocks = tiles < 256 ? tiles : 256;
            if (blocks < 1) blocks = 1;
            int nt     = tiles / blocks;
            internal_mfma<<<blocks, 512, 2 * BUFSZ, stream>>>(
                wordid, Eb, Wb, b_iou, b_Uiou, b_Wf, b_Uf,
                h_prev, c_prev, h_cur, c_cur, b_out, out, l, t0, nt);
        }
        int blocksR = (T / 4 < 4096) ? ((T + 3) / 4) : 4096;
        if (blocksR < 1) blocksR = 1;
        logits_root<<<blocksR, 256, 0, stream>>>(hB, W_out, b_out, out, T, t0);
    }
}